// Round 4
// baseline (250.941 us; speedup 1.0000x reference)
//
#include <hip/hip_runtime.h>
#include <hip/hip_bf16.h>
#include <stdint.h>

typedef __attribute__((ext_vector_type(4))) float f32x4;
typedef __attribute__((ext_vector_type(8))) short s16x8;
typedef unsigned short u16;

// ---------------- helpers ----------------

__device__ __forceinline__ void gl_lds16(const void* g, void* l) {
  __builtin_amdgcn_global_load_lds(
      (const __attribute__((address_space(1))) void*)g,
      (__attribute__((address_space(3))) void*)l,
      16, 0, 0);
}

// Stage 128 rows x 64 bytes (32 bf16) global->LDS.
// LDS is linear [row][slot0..3 of 16B]; source chunk is pre-swizzled so that
// LDS[row][s] holds global chunk (s ^ swz(row)), swz(row) = (row>>1)&3.
// (global_load_lds: per-lane SOURCE addr, wave-uniform LDS base + lane*16.)
__device__ __forceinline__ void stage128x32(const char* g0, int stride, char* lds, int tid) {
  int w = tid >> 6;
#pragma unroll
  for (int h = 0; h < 2; ++h) {
    int c = tid + h * 256;           // chunk 0..511
    int row = c >> 2;
    int g = (c & 3) ^ ((row >> 1) & 3);
    gl_lds16(g0 + (size_t)row * stride + g * 16, lds + h * 4096 + w * 1024);
  }
}

__device__ __forceinline__ s16x8 frag_ld(const char* lds, int row, int g) {
  int slot = g ^ ((row >> 1) & 3);
  return *(const s16x8*)(lds + row * 64 + slot * 16);
}

// One BK=32 step: 8 ds_read_b128 + 16 mfma per wave. Wave owns 64x64 quadrant (wr,wc).
__device__ __forceinline__ void mfma_step(const char* As, const char* Bs,
                                          f32x4 acc[4][4], int lane, int wr, int wc) {
  s16x8 af[4], bf[4];
  int lr = lane & 15, g = lane >> 4;
#pragma unroll
  for (int m = 0; m < 4; ++m) af[m] = frag_ld(As, wr * 64 + m * 16 + lr, g);
#pragma unroll
  for (int n = 0; n < 4; ++n) bf[n] = frag_ld(Bs, wc * 64 + n * 16 + lr, g);
#pragma unroll
  for (int m = 0; m < 4; ++m)
#pragma unroll
    for (int n = 0; n < 4; ++n)
      acc[m][n] = __builtin_amdgcn_mfma_f32_16x16x32_bf16(af[m], bf[n], acc[m][n], 0, 0, 0);
}

__device__ __forceinline__ u16 f2bf(float v) {
  __hip_bfloat16 h = __float2bfloat16(v);
  return *(u16*)&h;
}

// ---------------- kernels ----------------

// copy x -> out[:, :512] (fp32) and convert x -> Xb (bf16). 8 floats/thread.
__global__ __launch_bounds__(256) void prep_x(const float* __restrict__ x,
                                              float* __restrict__ out,
                                              u16* __restrict__ Xb) {
  size_t i = ((size_t)blockIdx.x * 256 + threadIdx.x) * 8;
  size_t tk = i >> 9;
  int c = (int)(i & 511);
  float4 a = *(const float4*)(x + i);
  float4 b = *(const float4*)(x + i + 4);
  *(float4*)(out + tk * 1024 + c) = a;
  *(float4*)(out + tk * 1024 + c + 4) = b;
  union { u16 us[8]; uint4 v; } pk;
  pk.us[0] = f2bf(a.x); pk.us[1] = f2bf(a.y); pk.us[2] = f2bf(a.z); pk.us[3] = f2bf(a.w);
  pk.us[4] = f2bf(b.x); pk.us[5] = f2bf(b.y); pk.us[6] = f2bf(b.z); pk.us[7] = f2bf(b.w);
  *(uint4*)(Xb + i) = pk.v;
}

// convert Wq|Wk|Wv -> Wb bf16 [1536][512]
__global__ __launch_bounds__(256) void prep_w(const float* __restrict__ Wq,
                                              const float* __restrict__ Wk,
                                              const float* __restrict__ Wv,
                                              u16* __restrict__ Wb) {
  int t = blockIdx.x * 256 + threadIdx.x;   // 98304 threads
  int m = t >> 15;                          // 32768 threads per matrix
  int off = (t & 32767) * 8;
  const float* W = (m == 0) ? Wq : ((m == 1) ? Wk : Wv);
  union { u16 us[8]; uint4 v; } pk;
#pragma unroll
  for (int k = 0; k < 8; ++k) pk.us[k] = f2bf(W[off + k]);
  *(uint4*)(Wb + (size_t)m * 262144 + off) = pk.v;
}

// Q/K/V fused GEMM: [16384x512] x [1536x512]^T -> Q,K,V bf16 (+bias)
__global__ __launch_bounds__(256, 2) void qkv_gemm(const u16* __restrict__ Xb, const u16* __restrict__ Wb,
                                                   const float* __restrict__ bq, const float* __restrict__ bk,
                                                   const float* __restrict__ bv,
                                                   u16* __restrict__ Qb, u16* __restrict__ Kb, u16* __restrict__ Vb) {
  __shared__ __align__(16) char As[8192], Bs[8192];
  int tid = threadIdx.x, lane = tid & 63, wid = tid >> 6;
  int wr = wid >> 1, wc = wid & 1;
  int bm = blockIdx.x, bn = blockIdx.y;
  const char* Ab = (const char*)(Xb + (size_t)bm * 128 * 512);
  const char* Bb = (const char*)(Wb + (size_t)bn * 128 * 512);
  f32x4 acc[4][4] = {};
  for (int ks = 0; ks < 16; ++ks) {
    stage128x32(Ab + ks * 64, 1024, As, tid);
    stage128x32(Bb + ks * 64, 1024, Bs, tid);
    __syncthreads();
    mfma_step(As, Bs, acc, lane, wr, wc);
    __syncthreads();
  }
  // C/D: col = lane&15, row = (lane>>4)*4 + reg
  int row0 = bm * 128 + wr * 64 + (lane >> 4) * 4;
  int col0 = bn * 128 + wc * 64 + (lane & 15);
#pragma unroll
  for (int n = 0; n < 4; ++n) {
    int cg = col0 + n * 16;
    int sel = cg >> 9, nn = cg & 511;
    const float* bias = (sel == 0) ? bq : ((sel == 1) ? bk : bv);
    u16* O = (sel == 0) ? Qb : ((sel == 1) ? Kb : Vb);
    float bb = bias[nn];
#pragma unroll
    for (int m = 0; m < 4; ++m)
#pragma unroll
      for (int r = 0; r < 4; ++r)
        O[(size_t)(row0 + m * 16 + r) * 512 + nn] = f2bf(acc[m][n][r] + bb);
  }
}

// E = exp(QK^T/sqrt(512)) masked (j<=i), colsum_j += sum_i E_ij. Block-causal tiles.
__global__ __launch_bounds__(256, 2) void scores(const u16* __restrict__ Qb, const u16* __restrict__ Kb,
                                                 u16* __restrict__ E, float* __restrict__ colsum) {
  __shared__ __align__(16) char As[8192], Bs[8192];
  __shared__ float colred[128];
  int tid = threadIdx.x, lane = tid & 63, wid = tid >> 6;
  int wr = wid >> 1, wc = wid & 1;
  int bx = blockIdx.x;
  int b = bx / 136, t = bx % 136;
  int bi = (int)((sqrtf(8.f * t + 1.f) - 1.f) * 0.5f);
  while ((bi + 1) * (bi + 2) / 2 <= t) ++bi;
  while (bi * (bi + 1) / 2 > t) --bi;
  int bj = t - bi * (bi + 1) / 2;
  const char* Ab = (const char*)(Qb + ((size_t)b * 2048 + bi * 128) * 512);
  const char* Bb = (const char*)(Kb + ((size_t)b * 2048 + bj * 128) * 512);
  f32x4 acc[4][4] = {};
  for (int ks = 0; ks < 16; ++ks) {
    stage128x32(Ab + ks * 64, 1024, As, tid);
    stage128x32(Bb + ks * 64, 1024, Bs, tid);
    __syncthreads();
    mfma_step(As, Bs, acc, lane, wr, wc);
    __syncthreads();
  }
  if (tid < 128) colred[tid] = 0.f;
  __syncthreads();
  const float expc = 1.4426950408889634f / 22.627416997969522f; // log2(e)/sqrt(512)
  int i0 = bi * 128 + wr * 64 + (lane >> 4) * 4;
  u16* Eb = E + (size_t)b * 2048 * 2048;
#pragma unroll
  for (int n = 0; n < 4; ++n) {
    int jj = wc * 64 + n * 16 + (lane & 15);
    int jg = bj * 128 + jj;
    float csum = 0.f;
#pragma unroll
    for (int m = 0; m < 4; ++m)
#pragma unroll
      for (int r = 0; r < 4; ++r) {
        int ig = i0 + m * 16 + r;
        float e = (jg > ig) ? 0.f : exp2f(acc[m][n][r] * expc);
        Eb[(size_t)ig * 2048 + jg] = f2bf(e);
        csum += e;
      }
    csum += __shfl_xor(csum, 16);
    csum += __shfl_xor(csum, 32);
    if ((lane >> 4) == 0) atomicAdd(&colred[jj], csum);
  }
  __syncthreads();
  if (tid < 128) atomicAdd(&colsum[b * 2048 + bj * 128 + tid], colred[tid]);
}

// Vt[b][n][j] = Vb[b][j][n] / colsum[b][j]  (64x64 tiles)
__global__ __launch_bounds__(256) void vtrans(const u16* __restrict__ Vb, const float* __restrict__ colsum,
                                              u16* __restrict__ Vt) {
  __shared__ u16 tile[64][72];
  __shared__ float scale[64];
  int b = blockIdx.z, j0 = blockIdx.x * 64, n0 = blockIdx.y * 64;
  int t = threadIdx.x;
  if (t < 64) scale[t] = 1.f / colsum[b * 2048 + j0 + t];
#pragma unroll
  for (int p = 0; p < 2; ++p) {
    int c = t + p * 256, r = c >> 3, nf = (c & 7) * 8;
    *(uint4*)&tile[r][nf] = *(const uint4*)(Vb + ((size_t)(b * 2048 + j0 + r)) * 512 + n0 + nf);
  }
  __syncthreads();
#pragma unroll
  for (int p = 0; p < 2; ++p) {
    int c = t + p * 256, n = c >> 3, jf = (c & 7) * 8;
    union { u16 us[8]; uint4 v; } pk;
#pragma unroll
    for (int k = 0; k < 8; ++k) {
      uint32_t bits = ((uint32_t)tile[jf + k][n]) << 16;
      float v; __builtin_memcpy(&v, &bits, 4);
      pk.us[k] = f2bf(v * scale[jf + k]);
    }
    *(uint4*)(Vt + ((size_t)(b * 512 + n0 + n)) * 2048 + j0 + jf) = pk.v;
  }
}

// out[:, 512:] = E @ V'  (causal K-loop, mi-descending for balance)
__global__ __launch_bounds__(256, 2) void pv_gemm(const u16* __restrict__ E, const u16* __restrict__ Vt,
                                                  float* __restrict__ out) {
  __shared__ __align__(16) char As[8192], Bs[8192];
  int tid = threadIdx.x, lane = tid & 63, wid = tid >> 6;
  int wr = wid >> 1, wc = wid & 1;
  int bx = blockIdx.x;
  int b = bx >> 6, rem = bx & 63;
  int mi = 15 - (rem >> 2), nj = rem & 3;
  const char* Ab = (const char*)(E + ((size_t)b * 2048 + mi * 128) * 2048);
  const char* Bb = (const char*)(Vt + ((size_t)b * 512 + nj * 128) * 2048);
  int NK = (mi + 1) * 4;
  f32x4 acc[4][4] = {};
  for (int ks = 0; ks < NK; ++ks) {
    stage128x32(Ab + ks * 64, 4096, As, tid);
    stage128x32(Bb + ks * 64, 4096, Bs, tid);
    __syncthreads();
    mfma_step(As, Bs, acc, lane, wr, wc);
    __syncthreads();
  }
  int i0 = mi * 128 + wr * 64 + (lane >> 4) * 4;
  int n0 = 512 + nj * 128 + wc * 64 + (lane & 15);
  float* ob = out + (size_t)b * 2048 * 1024;
#pragma unroll
  for (int m = 0; m < 4; ++m)
#pragma unroll
    for (int n = 0; n < 4; ++n)
#pragma unroll
      for (int r = 0; r < 4; ++r)
        ob[(size_t)(i0 + m * 16 + r) * 1024 + n0 + n * 16] = acc[m][n][r];
}

// ---------------- launch ----------------

extern "C" void kernel_launch(void* const* d_in, const int* in_sizes, int n_in,
                              void* d_out, int out_size, void* d_ws, size_t ws_size,
                              hipStream_t stream) {
  const float* x  = (const float*)d_in[0];
  const float* Wq = (const float*)d_in[1];
  const float* bq = (const float*)d_in[2];
  const float* Wk = (const float*)d_in[3];
  const float* bk = (const float*)d_in[4];
  const float* Wv = (const float*)d_in[5];
  const float* bv = (const float*)d_in[6];
  float* out = (float*)d_out;
  char* ws = (char*)d_ws;

  // ws layout (bytes): Xb 16MB | Wb 1.5MB | Qb 16MB | Kb 16MB | Vb 16MB | Vt 16MB | E 64MB | colsum 64KB
  u16* Xb = (u16*)(ws);
  u16* Wb = (u16*)(ws + 16777216);
  u16* Qb = (u16*)(ws + 18350080);
  u16* Kb = (u16*)(ws + 35127296);
  u16* Vb = (u16*)(ws + 51904512);
  u16* Vt = (u16*)(ws + 68681728);
  u16* E  = (u16*)(ws + 85458944);
  float* colsum = (float*)(ws + 152567808);

  hipMemsetAsync(colsum, 0, 8 * 2048 * 4, stream);
  prep_x<<<4096, 256, 0, stream>>>(x, out, Xb);
  prep_w<<<384, 256, 0, stream>>>(Wq, Wk, Wv, Wb);
  qkv_gemm<<<dim3(128, 12), 256, 0, stream>>>(Xb, Wb, bq, bk, bv, Qb, Kb, Vb);
  scores<<<1088, 256, 0, stream>>>(Qb, Kb, E, colsum);
  vtrans<<<dim3(32, 8, 8), 256, 0, stream>>>(Vb, colsum, Vt);
  pv_gemm<<<512, 256, 0, stream>>>(E, Vt, out);
}

// Round 5
// 233.565 us; speedup vs baseline: 1.0744x; 1.0744x over previous
//
#include <hip/hip_runtime.h>
#include <hip/hip_bf16.h>
#include <stdint.h>

typedef __attribute__((ext_vector_type(4))) float f32x4;
typedef __attribute__((ext_vector_type(8))) short s16x8;
typedef unsigned short u16;

// ---------------- helpers ----------------

__device__ __forceinline__ void gl_lds16(const void* g, void* l) {
  __builtin_amdgcn_global_load_lds(
      (const __attribute__((address_space(1))) void*)g,
      (__attribute__((address_space(3))) void*)l,
      16, 0, 0);
}

// Stage 128 rows x 64 bytes (32 bf16) global->LDS.
// LDS linear [row][slot0..3 of 16B]; source pre-swizzled: LDS[row][s] holds
// global chunk s ^ ((row>>1)&3)  (rule #21: inverse-swz source + swz read).
__device__ __forceinline__ void stage128x32(const char* g0, int stride, char* lds, int tid) {
  int w = tid >> 6;
#pragma unroll
  for (int h = 0; h < 2; ++h) {
    int c = tid + h * 256;           // chunk 0..511
    int row = c >> 2;
    int g = (c & 3) ^ ((row >> 1) & 3);
    gl_lds16(g0 + (size_t)row * stride + g * 16, lds + h * 4096 + w * 1024);
  }
}

__device__ __forceinline__ s16x8 frag_ld(const char* lds, int row, int g) {
  int slot = g ^ ((row >> 1) & 3);
  return *(const s16x8*)(lds + row * 64 + slot * 16);
}

// One BK=32 step: 8 ds_read_b128 + 16 mfma per wave. Wave owns 64x64 quadrant (wr,wc).
__device__ __forceinline__ void mfma_step(const char* As, const char* Bs,
                                          f32x4 acc[4][4], int lane, int wr, int wc) {
  s16x8 af[4], bf[4];
  int lr = lane & 15, g = lane >> 4;
#pragma unroll
  for (int m = 0; m < 4; ++m) af[m] = frag_ld(As, wr * 64 + m * 16 + lr, g);
#pragma unroll
  for (int n = 0; n < 4; ++n) bf[n] = frag_ld(Bs, wc * 64 + n * 16 + lr, g);
#pragma unroll
  for (int m = 0; m < 4; ++m)
#pragma unroll
    for (int n = 0; n < 4; ++n)
      acc[m][n] = __builtin_amdgcn_mfma_f32_16x16x32_bf16(af[m], bf[n], acc[m][n], 0, 0, 0);
}

__device__ __forceinline__ u16 f2bf(float v) {
  __hip_bfloat16 h = __float2bfloat16(v);
  return *(u16*)&h;
}

// ---------------- kernels ----------------

// copy x -> out[:, :512] (fp32) and convert x -> Xb (bf16). 8 floats/thread.
__global__ __launch_bounds__(256) void prep_x(const float* __restrict__ x,
                                              float* __restrict__ out,
                                              u16* __restrict__ Xb) {
  size_t i = ((size_t)blockIdx.x * 256 + threadIdx.x) * 8;
  size_t tk = i >> 9;
  int c = (int)(i & 511);
  float4 a = *(const float4*)(x + i);
  float4 b = *(const float4*)(x + i + 4);
  *(float4*)(out + tk * 1024 + c) = a;
  *(float4*)(out + tk * 1024 + c + 4) = b;
  union { u16 us[8]; uint4 v; } pk;
  pk.us[0] = f2bf(a.x); pk.us[1] = f2bf(a.y); pk.us[2] = f2bf(a.z); pk.us[3] = f2bf(a.w);
  pk.us[4] = f2bf(b.x); pk.us[5] = f2bf(b.y); pk.us[6] = f2bf(b.z); pk.us[7] = f2bf(b.w);
  *(uint4*)(Xb + i) = pk.v;
}

// convert Wq|Wk|Wv -> Wb bf16 [1536][512]
__global__ __launch_bounds__(256) void prep_w(const float* __restrict__ Wq,
                                              const float* __restrict__ Wk,
                                              const float* __restrict__ Wv,
                                              u16* __restrict__ Wb) {
  int t = blockIdx.x * 256 + threadIdx.x;   // 98304 threads
  int m = t >> 15;                          // 32768 threads per matrix
  int off = (t & 32767) * 8;
  const float* W = (m == 0) ? Wq : ((m == 1) ? Wk : Wv);
  union { u16 us[8]; uint4 v; } pk;
#pragma unroll
  for (int k = 0; k < 8; ++k) pk.us[k] = f2bf(W[off + k]);
  *(uint4*)(Wb + (size_t)m * 262144 + off) = pk.v;
}

// Q/K/V fused GEMM: [16384x512] x [1536x512]^T -> Q,K,V bf16 (+bias)
// 2-phase double-buffered K-loop (prefetch k+1 during compute k).
__global__ __launch_bounds__(256, 4) void qkv_gemm(const u16* __restrict__ Xb, const u16* __restrict__ Wb,
                                                   const float* __restrict__ bq, const float* __restrict__ bk,
                                                   const float* __restrict__ bv,
                                                   u16* __restrict__ Qb, u16* __restrict__ Kb, u16* __restrict__ Vb) {
  __shared__ __align__(16) char As[2][8192], Bs[2][8192];
  int tid = threadIdx.x, lane = tid & 63, wid = tid >> 6;
  int wr = wid >> 1, wc = wid & 1;
  int bm = blockIdx.x, bn = blockIdx.y;
  const char* Ab = (const char*)(Xb + (size_t)bm * 128 * 512);
  const char* Bb = (const char*)(Wb + (size_t)bn * 128 * 512);
  f32x4 acc[4][4] = {};
  stage128x32(Ab, 1024, As[0], tid);
  stage128x32(Bb, 1024, Bs[0], tid);
  __syncthreads();
  for (int ks = 0; ks < 16; ++ks) {
    int cur = ks & 1;
    if (ks + 1 < 16) {
      stage128x32(Ab + (ks + 1) * 64, 1024, As[cur ^ 1], tid);
      stage128x32(Bb + (ks + 1) * 64, 1024, Bs[cur ^ 1], tid);
    }
    mfma_step(As[cur], Bs[cur], acc, lane, wr, wc);
    __syncthreads();
  }
  // C/D: col = lane&15, row = (lane>>4)*4 + reg
  int row0 = bm * 128 + wr * 64 + (lane >> 4) * 4;
  int col0 = bn * 128 + wc * 64 + (lane & 15);
#pragma unroll
  for (int n = 0; n < 4; ++n) {
    int cg = col0 + n * 16;
    int sel = cg >> 9, nn = cg & 511;
    const float* bias = (sel == 0) ? bq : ((sel == 1) ? bk : bv);
    u16* O = (sel == 0) ? Qb : ((sel == 1) ? Kb : Vb);
    float bb = bias[nn];
#pragma unroll
    for (int m = 0; m < 4; ++m)
#pragma unroll
      for (int r = 0; r < 4; ++r)
        O[(size_t)(row0 + m * 16 + r) * 512 + nn] = f2bf(acc[m][n][r] + bb);
  }
}

// E = exp(QK^T/sqrt(512)) masked (j<=i), colsum_j += sum_i E_ij.
// XCD-chunked: 1088 = 8*136, each XCD owns one batch (Q+K = 4MB fits its L2).
__global__ __launch_bounds__(256, 4) void scores(const u16* __restrict__ Qb, const u16* __restrict__ Kb,
                                                 u16* __restrict__ E, float* __restrict__ colsum) {
  __shared__ __align__(16) char As[2][8192], Bs[2][8192];
  __shared__ float colred[128];
  int tid = threadIdx.x, lane = tid & 63, wid = tid >> 6;
  int wr = wid >> 1, wc = wid & 1;
  int d = blockIdx.x;
  int id = (d & 7) * 136 + (d >> 3);   // bijective: round-robin -> chunked
  int b = id / 136, t = id - b * 136;
  int bi = (int)((sqrtf(8.f * t + 1.f) - 1.f) * 0.5f);
  while ((bi + 1) * (bi + 2) / 2 <= t) ++bi;
  while (bi * (bi + 1) / 2 > t) --bi;
  int bj = t - bi * (bi + 1) / 2;
  const char* Ab = (const char*)(Qb + ((size_t)b * 2048 + bi * 128) * 512);
  const char* Bb = (const char*)(Kb + ((size_t)b * 2048 + bj * 128) * 512);
  f32x4 acc[4][4] = {};
  stage128x32(Ab, 1024, As[0], tid);
  stage128x32(Bb, 1024, Bs[0], tid);
  __syncthreads();
  for (int ks = 0; ks < 16; ++ks) {
    int cur = ks & 1;
    if (ks + 1 < 16) {
      stage128x32(Ab + (ks + 1) * 64, 1024, As[cur ^ 1], tid);
      stage128x32(Bb + (ks + 1) * 64, 1024, Bs[cur ^ 1], tid);
    }
    mfma_step(As[cur], Bs[cur], acc, lane, wr, wc);
    __syncthreads();
  }
  if (tid < 128) colred[tid] = 0.f;
  __syncthreads();
  const float expc = 1.4426950408889634f / 22.627416997969522f; // log2(e)/sqrt(512)
  int i0 = bi * 128 + wr * 64 + (lane >> 4) * 4;
  u16* Eb = E + (size_t)b * 2048 * 2048;
#pragma unroll
  for (int n = 0; n < 4; ++n) {
    int jj = wc * 64 + n * 16 + (lane & 15);
    int jg = bj * 128 + jj;
    float csum = 0.f;
#pragma unroll
    for (int m = 0; m < 4; ++m)
#pragma unroll
      for (int r = 0; r < 4; ++r) {
        int ig = i0 + m * 16 + r;
        float e = (jg > ig) ? 0.f : exp2f(acc[m][n][r] * expc);
        Eb[(size_t)ig * 2048 + jg] = f2bf(e);
        csum += e;
      }
    csum += __shfl_xor(csum, 16);
    csum += __shfl_xor(csum, 32);
    if ((lane >> 4) == 0) atomicAdd(&colred[jj], csum);
  }
  __syncthreads();
  if (tid < 128) atomicAdd(&colsum[b * 2048 + bj * 128 + tid], colred[tid]);
}

// Vt[b][n][j] = Vb[b][j][n] / colsum[b][j]  (64x64 tiles)
__global__ __launch_bounds__(256) void vtrans(const u16* __restrict__ Vb, const float* __restrict__ colsum,
                                              u16* __restrict__ Vt) {
  __shared__ u16 tile[64][72];
  __shared__ float scale[64];
  int b = blockIdx.z, j0 = blockIdx.x * 64, n0 = blockIdx.y * 64;
  int t = threadIdx.x;
  if (t < 64) scale[t] = 1.f / colsum[b * 2048 + j0 + t];
#pragma unroll
  for (int p = 0; p < 2; ++p) {
    int c = t + p * 256, r = c >> 3, nf = (c & 7) * 8;
    *(uint4*)&tile[r][nf] = *(const uint4*)(Vb + ((size_t)(b * 2048 + j0 + r)) * 512 + n0 + nf);
  }
  __syncthreads();
#pragma unroll
  for (int p = 0; p < 2; ++p) {
    int c = t + p * 256, n = c >> 3, jf = (c & 7) * 8;
    union { u16 us[8]; uint4 v; } pk;
#pragma unroll
    for (int k = 0; k < 8; ++k) {
      uint32_t bits = ((uint32_t)tile[jf + k][n]) << 16;
      float v; __builtin_memcpy(&v, &bits, 4);
      pk.us[k] = f2bf(v * scale[jf + k]);
    }
    *(uint4*)(Vt + ((size_t)(b * 512 + n0 + n)) * 2048 + j0 + jf) = pk.v;
  }
}

// out[:, 512:] = E @ V'. XCD-chunked: 512 = 8*64, one batch per XCD;
// consecutive ids share the E row-panel (mi) across the 4 nj tiles.
__global__ __launch_bounds__(256, 4) void pv_gemm(const u16* __restrict__ E, const u16* __restrict__ Vt,
                                                  float* __restrict__ out) {
  __shared__ __align__(16) char As[2][8192], Bs[2][8192];
  int tid = threadIdx.x, lane = tid & 63, wid = tid >> 6;
  int wr = wid >> 1, wc = wid & 1;
  int d = blockIdx.x;
  int id = (d & 7) * 64 + (d >> 3);    // bijective: round-robin -> chunked
  int b = id >> 6, rem = id & 63;
  int mi = 15 - (rem >> 2), nj = rem & 3;
  const char* Ab = (const char*)(E + ((size_t)b * 2048 + mi * 128) * 2048);
  const char* Bb = (const char*)(Vt + ((size_t)b * 512 + nj * 128) * 2048);
  int NK = (mi + 1) * 4;
  f32x4 acc[4][4] = {};
  stage128x32(Ab, 4096, As[0], tid);
  stage128x32(Bb, 4096, Bs[0], tid);
  __syncthreads();
  for (int ks = 0; ks < NK; ++ks) {
    int cur = ks & 1;
    if (ks + 1 < NK) {
      stage128x32(Ab + (ks + 1) * 64, 4096, As[cur ^ 1], tid);
      stage128x32(Bb + (ks + 1) * 64, 4096, Bs[cur ^ 1], tid);
    }
    mfma_step(As[cur], Bs[cur], acc, lane, wr, wc);
    __syncthreads();
  }
  int i0 = mi * 128 + wr * 64 + (lane >> 4) * 4;
  int n0 = 512 + nj * 128 + wc * 64 + (lane & 15);
  float* ob = out + (size_t)b * 2048 * 1024;
#pragma unroll
  for (int m = 0; m < 4; ++m)
#pragma unroll
    for (int n = 0; n < 4; ++n)
#pragma unroll
      for (int r = 0; r < 4; ++r)
        ob[(size_t)(i0 + m * 16 + r) * 1024 + n0 + n * 16] = acc[m][n][r];
}

// ---------------- launch ----------------

extern "C" void kernel_launch(void* const* d_in, const int* in_sizes, int n_in,
                              void* d_out, int out_size, void* d_ws, size_t ws_size,
                              hipStream_t stream) {
  const float* x  = (const float*)d_in[0];
  const float* Wq = (const float*)d_in[1];
  const float* bq = (const float*)d_in[2];
  const float* Wk = (const float*)d_in[3];
  const float* bk = (const float*)d_in[4];
  const float* Wv = (const float*)d_in[5];
  const float* bv = (const float*)d_in[6];
  float* out = (float*)d_out;
  char* ws = (char*)d_ws;

  // ws layout (bytes): Xb 16MB | Wb 1.5MB | Qb 16MB | Kb 16MB | Vb 16MB | Vt 16MB | E 64MB | colsum 64KB
  u16* Xb = (u16*)(ws);
  u16* Wb = (u16*)(ws + 16777216);
  u16* Qb = (u16*)(ws + 18350080);
  u16* Kb = (u16*)(ws + 35127296);
  u16* Vb = (u16*)(ws + 51904512);
  u16* Vt = (u16*)(ws + 68681728);
  u16* E  = (u16*)(ws + 85458944);
  float* colsum = (float*)(ws + 152567808);

  hipMemsetAsync(colsum, 0, 8 * 2048 * 4, stream);
  prep_x<<<4096, 256, 0, stream>>>(x, out, Xb);
  prep_w<<<384, 256, 0, stream>>>(Wq, Wk, Wv, Wb);
  qkv_gemm<<<dim3(128, 12), 256, 0, stream>>>(Xb, Wb, bq, bk, bv, Qb, Kb, Vb);
  scores<<<1088, 256, 0, stream>>>(Qb, Kb, E, colsum);
  vtrans<<<dim3(32, 8, 8), 256, 0, stream>>>(Vb, colsum, Vt);
  pv_gemm<<<512, 256, 0, stream>>>(E, Vt, out);
}

// Round 6
// 225.644 us; speedup vs baseline: 1.1121x; 1.0351x over previous
//
#include <hip/hip_runtime.h>
#include <hip/hip_bf16.h>
#include <stdint.h>

typedef __attribute__((ext_vector_type(4))) float f32x4;
typedef __attribute__((ext_vector_type(8))) short s16x8;
typedef unsigned short u16;

// ---------------- helpers ----------------

__device__ __forceinline__ void gl_lds16(const void* g, void* l) {
  __builtin_amdgcn_global_load_lds(
      (const __attribute__((address_space(1))) void*)g,
      (__attribute__((address_space(3))) void*)l,
      16, 0, 0);
}

// Stage 128 rows x 64 bytes (32 bf16) global->LDS.
// LDS linear [row][slot0..3 of 16B]; source pre-swizzled: LDS[row][s] holds
// global chunk s ^ ((row>>1)&3)  (rule #21: inverse-swz source + swz read).
__device__ __forceinline__ void stage128x32(const char* g0, int stride, char* lds, int tid) {
  int w = tid >> 6;
#pragma unroll
  for (int h = 0; h < 2; ++h) {
    int c = tid + h * 256;           // chunk 0..511
    int row = c >> 2;
    int g = (c & 3) ^ ((row >> 1) & 3);
    gl_lds16(g0 + (size_t)row * stride + g * 16, lds + h * 4096 + w * 1024);
  }
}

__device__ __forceinline__ s16x8 frag_ld(const char* lds, int row, int g) {
  int slot = g ^ ((row >> 1) & 3);
  return *(const s16x8*)(lds + row * 64 + slot * 16);
}

// One BK=32 step: 8 ds_read_b128 + 16 mfma per wave. Wave owns 64x64 quadrant (wr,wc).
__device__ __forceinline__ void mfma_step(const char* As, const char* Bs,
                                          f32x4 acc[4][4], int lane, int wr, int wc) {
  s16x8 af[4], bf[4];
  int lr = lane & 15, g = lane >> 4;
#pragma unroll
  for (int m = 0; m < 4; ++m) af[m] = frag_ld(As, wr * 64 + m * 16 + lr, g);
#pragma unroll
  for (int n = 0; n < 4; ++n) bf[n] = frag_ld(Bs, wc * 64 + n * 16 + lr, g);
#pragma unroll
  for (int m = 0; m < 4; ++m)
#pragma unroll
    for (int n = 0; n < 4; ++n)
      acc[m][n] = __builtin_amdgcn_mfma_f32_16x16x32_bf16(af[m], bf[n], acc[m][n], 0, 0, 0);
}

__device__ __forceinline__ u16 f2bf(float v) {
  __hip_bfloat16 h = __float2bfloat16(v);
  return *(u16*)&h;
}

// Deep-pipelined K-loop core: 3 LDS buffers, prefetch depth 2, counted vmcnt.
// Barrier = "lgkmcnt(0) vmcnt(N); s_barrier": every wave's ds_reads complete
// before arrival (safe buffer overwrite), and only the OLDEST stage (4 gl_lds)
// is drained -- the newer 4 stay in flight across the barrier (T4 mechanism).
#define KLOOP(Ab, Bb, stride, NK)                                              \
  {                                                                            \
    stage128x32((Ab), (stride), As[0], tid);                                   \
    stage128x32((Bb), (stride), Bs[0], tid);                                   \
    stage128x32((Ab) + 64, (stride), As[1], tid);                              \
    stage128x32((Bb) + 64, (stride), Bs[1], tid);                              \
    int cur = 0;                                                               \
    for (int ks = 0; ks < (NK); ++ks) {                                        \
      if (ks + 1 < (NK)) {                                                     \
        asm volatile("s_waitcnt lgkmcnt(0) vmcnt(4)\n\ts_barrier" ::: "memory"); \
        if (ks + 2 < (NK)) {                                                   \
          int nb = cur + 2; if (nb >= 3) nb -= 3;                              \
          stage128x32((Ab) + (ks + 2) * 64, (stride), As[nb], tid);            \
          stage128x32((Bb) + (ks + 2) * 64, (stride), Bs[nb], tid);            \
        }                                                                      \
      } else {                                                                 \
        asm volatile("s_waitcnt lgkmcnt(0) vmcnt(0)\n\ts_barrier" ::: "memory"); \
      }                                                                        \
      mfma_step(As[cur], Bs[cur], acc, lane, wr, wc);                          \
      ++cur; if (cur >= 3) cur -= 3;                                           \
    }                                                                          \
  }

// ---------------- kernels ----------------

// copy x -> out[:, :512] (fp32) and convert x -> Xb (bf16). 8 floats/thread.
__global__ __launch_bounds__(256) void prep_x(const float* __restrict__ x,
                                              float* __restrict__ out,
                                              u16* __restrict__ Xb) {
  size_t i = ((size_t)blockIdx.x * 256 + threadIdx.x) * 8;
  size_t tk = i >> 9;
  int c = (int)(i & 511);
  float4 a = *(const float4*)(x + i);
  float4 b = *(const float4*)(x + i + 4);
  *(float4*)(out + tk * 1024 + c) = a;
  *(float4*)(out + tk * 1024 + c + 4) = b;
  union { u16 us[8]; uint4 v; } pk;
  pk.us[0] = f2bf(a.x); pk.us[1] = f2bf(a.y); pk.us[2] = f2bf(a.z); pk.us[3] = f2bf(a.w);
  pk.us[4] = f2bf(b.x); pk.us[5] = f2bf(b.y); pk.us[6] = f2bf(b.z); pk.us[7] = f2bf(b.w);
  *(uint4*)(Xb + i) = pk.v;
}

// convert Wq|Wk|Wv -> Wb bf16 [1536][512]
__global__ __launch_bounds__(256) void prep_w(const float* __restrict__ Wq,
                                              const float* __restrict__ Wk,
                                              const float* __restrict__ Wv,
                                              u16* __restrict__ Wb) {
  int t = blockIdx.x * 256 + threadIdx.x;   // 98304 threads
  int m = t >> 15;                          // 32768 threads per matrix
  int off = (t & 32767) * 8;
  const float* W = (m == 0) ? Wq : ((m == 1) ? Wk : Wv);
  union { u16 us[8]; uint4 v; } pk;
#pragma unroll
  for (int k = 0; k < 8; ++k) pk.us[k] = f2bf(W[off + k]);
  *(uint4*)(Wb + (size_t)m * 262144 + off) = pk.v;
}

// Q/K/V fused GEMM: [16384x512] x [1536x512]^T -> Q,K,V bf16 (+bias)
__global__ __launch_bounds__(256, 3) void qkv_gemm(const u16* __restrict__ Xb, const u16* __restrict__ Wb,
                                                   const float* __restrict__ bq, const float* __restrict__ bk,
                                                   const float* __restrict__ bv,
                                                   u16* __restrict__ Qb, u16* __restrict__ Kb, u16* __restrict__ Vb) {
  __shared__ __align__(16) char As[3][8192], Bs[3][8192];
  int tid = threadIdx.x, lane = tid & 63, wid = tid >> 6;
  int wr = wid >> 1, wc = wid & 1;
  int bm = blockIdx.x, bn = blockIdx.y;
  const char* Ab = (const char*)(Xb + (size_t)bm * 128 * 512);
  const char* Bb = (const char*)(Wb + (size_t)bn * 128 * 512);
  f32x4 acc[4][4] = {};
  KLOOP(Ab, Bb, 1024, 16);
  // C/D: col = lane&15, row = (lane>>4)*4 + reg
  int row0 = bm * 128 + wr * 64 + (lane >> 4) * 4;
  int col0 = bn * 128 + wc * 64 + (lane & 15);
#pragma unroll
  for (int n = 0; n < 4; ++n) {
    int cg = col0 + n * 16;
    int sel = cg >> 9, nn = cg & 511;
    const float* bias = (sel == 0) ? bq : ((sel == 1) ? bk : bv);
    u16* O = (sel == 0) ? Qb : ((sel == 1) ? Kb : Vb);
    float bb = bias[nn];
#pragma unroll
    for (int m = 0; m < 4; ++m)
#pragma unroll
      for (int r = 0; r < 4; ++r)
        O[(size_t)(row0 + m * 16 + r) * 512 + nn] = f2bf(acc[m][n][r] + bb);
  }
}

// E = exp(QK^T/sqrt(512)) masked (j<=i), colsum_j += sum_i E_ij.
// XCD-chunked: 1088 = 8*136, each XCD owns one batch (Q+K = 4MB fits its L2).
__global__ __launch_bounds__(256, 3) void scores(const u16* __restrict__ Qb, const u16* __restrict__ Kb,
                                                 u16* __restrict__ E, float* __restrict__ colsum) {
  __shared__ __align__(16) char As[3][8192], Bs[3][8192];
  __shared__ float colred[128];
  int tid = threadIdx.x, lane = tid & 63, wid = tid >> 6;
  int wr = wid >> 1, wc = wid & 1;
  int d = blockIdx.x;
  int id = (d & 7) * 136 + (d >> 3);   // bijective: round-robin -> chunked
  int b = id / 136, t = id - b * 136;
  int bi = (int)((sqrtf(8.f * t + 1.f) - 1.f) * 0.5f);
  while ((bi + 1) * (bi + 2) / 2 <= t) ++bi;
  while (bi * (bi + 1) / 2 > t) --bi;
  int bj = t - bi * (bi + 1) / 2;
  const char* Ab = (const char*)(Qb + ((size_t)b * 2048 + bi * 128) * 512);
  const char* Bb = (const char*)(Kb + ((size_t)b * 2048 + bj * 128) * 512);
  f32x4 acc[4][4] = {};
  KLOOP(Ab, Bb, 1024, 16);
  if (tid < 128) colred[tid] = 0.f;
  __syncthreads();
  const float expc = 1.4426950408889634f / 22.627416997969522f; // log2(e)/sqrt(512)
  int i0 = bi * 128 + wr * 64 + (lane >> 4) * 4;
  u16* Eb = E + (size_t)b * 2048 * 2048;
#pragma unroll
  for (int n = 0; n < 4; ++n) {
    int jj = wc * 64 + n * 16 + (lane & 15);
    int jg = bj * 128 + jj;
    float csum = 0.f;
#pragma unroll
    for (int m = 0; m < 4; ++m)
#pragma unroll
      for (int r = 0; r < 4; ++r) {
        int ig = i0 + m * 16 + r;
        float e = (jg > ig) ? 0.f : exp2f(acc[m][n][r] * expc);
        Eb[(size_t)ig * 2048 + jg] = f2bf(e);
        csum += e;
      }
    csum += __shfl_xor(csum, 16);
    csum += __shfl_xor(csum, 32);
    if ((lane >> 4) == 0) atomicAdd(&colred[jj], csum);
  }
  __syncthreads();
  if (tid < 128) atomicAdd(&colsum[b * 2048 + bj * 128 + tid], colred[tid]);
}

// Vt[b][n][j] = Vb[b][j][n] / colsum[b][j]  (64x64 tiles)
__global__ __launch_bounds__(256) void vtrans(const u16* __restrict__ Vb, const float* __restrict__ colsum,
                                              u16* __restrict__ Vt) {
  __shared__ u16 tile[64][72];
  __shared__ float scale[64];
  int b = blockIdx.z, j0 = blockIdx.x * 64, n0 = blockIdx.y * 64;
  int t = threadIdx.x;
  if (t < 64) scale[t] = 1.f / colsum[b * 2048 + j0 + t];
#pragma unroll
  for (int p = 0; p < 2; ++p) {
    int c = t + p * 256, r = c >> 3, nf = (c & 7) * 8;
    *(uint4*)&tile[r][nf] = *(const uint4*)(Vb + ((size_t)(b * 2048 + j0 + r)) * 512 + n0 + nf);
  }
  __syncthreads();
#pragma unroll
  for (int p = 0; p < 2; ++p) {
    int c = t + p * 256, n = c >> 3, jf = (c & 7) * 8;
    union { u16 us[8]; uint4 v; } pk;
#pragma unroll
    for (int k = 0; k < 8; ++k) {
      uint32_t bits = ((uint32_t)tile[jf + k][n]) << 16;
      float v; __builtin_memcpy(&v, &bits, 4);
      pk.us[k] = f2bf(v * scale[jf + k]);
    }
    *(uint4*)(Vt + ((size_t)(b * 512 + n0 + n)) * 2048 + j0 + jf) = pk.v;
  }
}

// out[:, 512:] = E @ V'. XCD-chunked: 512 = 8*64, one batch per XCD;
// consecutive ids share the E row-panel (mi) across the 4 nj tiles.
__global__ __launch_bounds__(256, 3) void pv_gemm(const u16* __restrict__ E, const u16* __restrict__ Vt,
                                                  float* __restrict__ out) {
  __shared__ __align__(16) char As[3][8192], Bs[3][8192];
  int tid = threadIdx.x, lane = tid & 63, wid = tid >> 6;
  int wr = wid >> 1, wc = wid & 1;
  int d = blockIdx.x;
  int id = (d & 7) * 64 + (d >> 3);    // bijective: round-robin -> chunked
  int b = id >> 6, rem = id & 63;
  int mi = 15 - (rem >> 2), nj = rem & 3;
  const char* Ab = (const char*)(E + ((size_t)b * 2048 + mi * 128) * 2048);
  const char* Bb = (const char*)(Vt + ((size_t)b * 512 + nj * 128) * 2048);
  int NK = (mi + 1) * 4;
  f32x4 acc[4][4] = {};
  KLOOP(Ab, Bb, 4096, NK);
  int i0 = mi * 128 + wr * 64 + (lane >> 4) * 4;
  int n0 = 512 + nj * 128 + wc * 64 + (lane & 15);
  float* ob = out + (size_t)b * 2048 * 1024;
#pragma unroll
  for (int m = 0; m < 4; ++m)
#pragma unroll
    for (int n = 0; n < 4; ++n)
#pragma unroll
      for (int r = 0; r < 4; ++r)
        ob[(size_t)(i0 + m * 16 + r) * 1024 + n0 + n * 16] = acc[m][n][r];
}

// ---------------- launch ----------------

extern "C" void kernel_launch(void* const* d_in, const int* in_sizes, int n_in,
                              void* d_out, int out_size, void* d_ws, size_t ws_size,
                              hipStream_t stream) {
  const float* x  = (const float*)d_in[0];
  const float* Wq = (const float*)d_in[1];
  const float* bq = (const float*)d_in[2];
  const float* Wk = (const float*)d_in[3];
  const float* bk = (const float*)d_in[4];
  const float* Wv = (const float*)d_in[5];
  const float* bv = (const float*)d_in[6];
  float* out = (float*)d_out;
  char* ws = (char*)d_ws;

  // ws layout (bytes): Xb 16MB | Wb 1.5MB | Qb 16MB | Kb 16MB | Vb 16MB | Vt 16MB | E 64MB | colsum 64KB
  u16* Xb = (u16*)(ws);
  u16* Wb = (u16*)(ws + 16777216);
  u16* Qb = (u16*)(ws + 18350080);
  u16* Kb = (u16*)(ws + 35127296);
  u16* Vb = (u16*)(ws + 51904512);
  u16* Vt = (u16*)(ws + 68681728);
  u16* E  = (u16*)(ws + 85458944);
  float* colsum = (float*)(ws + 152567808);

  hipMemsetAsync(colsum, 0, 8 * 2048 * 4, stream);
  prep_x<<<4096, 256, 0, stream>>>(x, out, Xb);
  prep_w<<<384, 256, 0, stream>>>(Wq, Wk, Wv, Wb);
  qkv_gemm<<<dim3(128, 12), 256, 0, stream>>>(Xb, Wb, bq, bk, bv, Qb, Kb, Vb);
  scores<<<1088, 256, 0, stream>>>(Qb, Kb, E, colsum);
  vtrans<<<dim3(32, 8, 8), 256, 0, stream>>>(Vb, colsum, Vt);
  pv_gemm<<<512, 256, 0, stream>>>(E, Vt, out);
}

// Round 8
// 221.194 us; speedup vs baseline: 1.1345x; 1.0201x over previous
//
#include <hip/hip_runtime.h>
#include <hip/hip_bf16.h>
#include <stdint.h>

typedef __attribute__((ext_vector_type(4))) float f32x4;
typedef __attribute__((ext_vector_type(8))) short s16x8;
typedef unsigned short u16;

// ---------------- helpers ----------------

__device__ __forceinline__ void gl_lds16(const void* g, void* l) {
  __builtin_amdgcn_global_load_lds(
      (const __attribute__((address_space(1))) void*)g,
      (__attribute__((address_space(3))) void*)l,
      16, 0, 0);
}

// Stage 128 rows x 64 bytes (32 bf16) global->LDS.
// LDS linear [row][slot0..3 of 16B]; source pre-swizzled: LDS[row][s] holds
// global chunk s ^ ((row>>1)&3)  (rule #21: inverse-swz source + swz read).
// PERM: LDS row jj holds GLOBAL row sigma(jj) = (jj&64) | 4*(jj&15) + ((jj&63)>>4)
// -> MFMA C-cols become 4-consecutive per lane (coalesced 8B epilogue stores).
template<bool PERM>
__device__ __forceinline__ void stage128x32(const char* g0, int stride, char* lds, int tid) {
  int w = tid >> 6;
#pragma unroll
  for (int h = 0; h < 2; ++h) {
    int c = tid + h * 256;           // chunk 0..511
    int row = c >> 2;
    int srow = row;
    if (PERM) srow = (row & 64) | ((row & 15) << 2) | ((row & 63) >> 4);
    int g = (c & 3) ^ ((row >> 1) & 3);
    gl_lds16(g0 + (size_t)srow * stride + g * 16, lds + h * 4096 + w * 1024);
  }
}

__device__ __forceinline__ s16x8 frag_ld(const char* lds, int row, int g) {
  int slot = g ^ ((row >> 1) & 3);
  return *(const s16x8*)(lds + row * 64 + slot * 16);
}

// One BK=32 step: 8 ds_read_b128 + 16 mfma per wave. Wave owns 64x64 quadrant (wr,wc).
__device__ __forceinline__ void mfma_step(const char* As, const char* Bs,
                                          f32x4 acc[4][4], int lane, int wr, int wc) {
  s16x8 af[4], bf[4];
  int lr = lane & 15, g = lane >> 4;
#pragma unroll
  for (int m = 0; m < 4; ++m) af[m] = frag_ld(As, wr * 64 + m * 16 + lr, g);
#pragma unroll
  for (int n = 0; n < 4; ++n) bf[n] = frag_ld(Bs, wc * 64 + n * 16 + lr, g);
#pragma unroll
  for (int m = 0; m < 4; ++m)
#pragma unroll
    for (int n = 0; n < 4; ++n)
      acc[m][n] = __builtin_amdgcn_mfma_f32_16x16x32_bf16(af[m], bf[n], acc[m][n], 0, 0, 0);
}

__device__ __forceinline__ u16 f2bf(float v) {
  __hip_bfloat16 h = __float2bfloat16(v);
  return *(u16*)&h;
}

// Deep-pipelined K-loop: 3 LDS buffers, prefetch depth 2, counted vmcnt
// (drain only the oldest stage at each barrier; newer 4 stay in flight).
#define KLOOP(Ab, Bb, stride, NK, PERMB)                                       \
  {                                                                            \
    stage128x32<false>((Ab), (stride), As[0], tid);                            \
    stage128x32<PERMB>((Bb), (stride), Bs[0], tid);                            \
    stage128x32<false>((Ab) + 64, (stride), As[1], tid);                       \
    stage128x32<PERMB>((Bb) + 64, (stride), Bs[1], tid);                       \
    int cur = 0;                                                               \
    for (int ks = 0; ks < (NK); ++ks) {                                        \
      if (ks + 1 < (NK)) {                                                     \
        asm volatile("s_waitcnt lgkmcnt(0) vmcnt(4)\n\ts_barrier" ::: "memory"); \
        if (ks + 2 < (NK)) {                                                   \
          int nb = cur + 2; if (nb >= 3) nb -= 3;                              \
          stage128x32<false>((Ab) + (ks + 2) * 64, (stride), As[nb], tid);     \
          stage128x32<PERMB>((Bb) + (ks + 2) * 64, (stride), Bs[nb], tid);     \
        }                                                                      \
      } else {                                                                 \
        asm volatile("s_waitcnt lgkmcnt(0) vmcnt(0)\n\ts_barrier" ::: "memory"); \
      }                                                                        \
      mfma_step(As[cur], Bs[cur], acc, lane, wr, wc);                          \
      ++cur; if (cur >= 3) cur -= 3;                                           \
    }                                                                          \
  }

// ---------------- kernels ----------------

// Fused prep: x -> out[:, :512] + Xb(bf16); W -> Wb(bf16); colsum -> 0.
__global__ __launch_bounds__(256) void prep(const float* __restrict__ x,
                                            const float* __restrict__ Wq,
                                            const float* __restrict__ Wk,
                                            const float* __restrict__ Wv,
                                            float* __restrict__ out,
                                            u16* __restrict__ Xb,
                                            u16* __restrict__ Wb,
                                            float* __restrict__ colsum) {
  int bx = blockIdx.x, tid = threadIdx.x;
  if (bx < 64) colsum[(bx << 8) + tid] = 0.f;
  if (bx < 4096) {
    size_t i = ((size_t)bx * 256 + tid) * 8;
    size_t tk = i >> 9;
    int c = (int)(i & 511);
    float4 a = *(const float4*)(x + i);
    float4 b = *(const float4*)(x + i + 4);
    *(float4*)(out + tk * 1024 + c) = a;
    *(float4*)(out + tk * 1024 + c + 4) = b;
    union { u16 us[8]; uint4 v; } pk;
    pk.us[0] = f2bf(a.x); pk.us[1] = f2bf(a.y); pk.us[2] = f2bf(a.z); pk.us[3] = f2bf(a.w);
    pk.us[4] = f2bf(b.x); pk.us[5] = f2bf(b.y); pk.us[6] = f2bf(b.z); pk.us[7] = f2bf(b.w);
    *(uint4*)(Xb + i) = pk.v;
  } else {
    int t = (bx - 4096) * 256 + tid;        // 0..98303
    int m = t >> 15;
    int off = (t & 32767) * 8;
    const float* W = (m == 0) ? Wq : ((m == 1) ? Wk : Wv);
    union { u16 us[8]; uint4 v; } pk;
#pragma unroll
    for (int k = 0; k < 8; ++k) pk.us[k] = f2bf(W[off + k]);
    *(uint4*)(Wb + (size_t)m * 262144 + off) = pk.v;
  }
}

// Q/K/V fused GEMM: [16384x512] x [1536x512]^T -> Q,K,V bf16 (+bias).
// B staged sigma-permuted: lane owns 4 consecutive out-cols -> 8B packed stores.
__global__ __launch_bounds__(256, 3) void qkv_gemm(const u16* __restrict__ Xb, const u16* __restrict__ Wb,
                                                   const float* __restrict__ bq, const float* __restrict__ bk,
                                                   const float* __restrict__ bv,
                                                   u16* __restrict__ Qb, u16* __restrict__ Kb, u16* __restrict__ Vb) {
  __shared__ __align__(16) char As[3][8192], Bs[3][8192];
  int tid = threadIdx.x, lane = tid & 63, wid = tid >> 6;
  int wr = wid >> 1, wc = wid & 1;
  int bm = blockIdx.x, bn = blockIdx.y;
  const char* Ab = (const char*)(Xb + (size_t)bm * 128 * 512);
  const char* Bb = (const char*)(Wb + (size_t)bn * 128 * 512);
  f32x4 acc[4][4] = {};
  KLOOP(Ab, Bb, 1024, 16, true);
  int row0 = bm * 128 + wr * 64 + (lane >> 4) * 4;
  int lr = lane & 15;
  int cg0 = bn * 128 + wc * 64 + lr * 4;      // 4-aligned, no 512-straddle
  int sel = cg0 >> 9, nn0 = cg0 & 511;
  const float* bias = (sel == 0) ? bq : ((sel == 1) ? bk : bv);
  u16* O = (sel == 0) ? Qb : ((sel == 1) ? Kb : Vb);
  float4 bb = *(const float4*)(bias + nn0);
#pragma unroll
  for (int m = 0; m < 4; ++m)
#pragma unroll
    for (int r = 0; r < 4; ++r) {
      union { u16 us[4]; uint2 v; } pk;
      pk.us[0] = f2bf(acc[m][0][r] + bb.x);
      pk.us[1] = f2bf(acc[m][1][r] + bb.y);
      pk.us[2] = f2bf(acc[m][2][r] + bb.z);
      pk.us[3] = f2bf(acc[m][3][r] + bb.w);
      *(uint2*)&O[(size_t)(row0 + m * 16 + r) * 512 + nn0] = pk.v;
    }
}

// E = exp(QK^T/sqrt(512)) masked (j<=i), colsum_j += sum_i E_ij.
// XCD-chunked (one batch per XCD); K staged sigma-permuted -> 8B packed E stores.
__global__ __launch_bounds__(256, 3) void scores(const u16* __restrict__ Qb, const u16* __restrict__ Kb,
                                                 u16* __restrict__ E, float* __restrict__ colsum) {
  __shared__ __align__(16) char As[3][8192], Bs[3][8192];
  __shared__ float colred[128];
  int tid = threadIdx.x, lane = tid & 63, wid = tid >> 6;
  int wr = wid >> 1, wc = wid & 1;
  int d = blockIdx.x;
  int id = (d & 7) * 136 + (d >> 3);   // bijective: round-robin -> chunked
  int b = id / 136, t = id - b * 136;
  int bi = (int)((sqrtf(8.f * t + 1.f) - 1.f) * 0.5f);
  while ((bi + 1) * (bi + 2) / 2 <= t) ++bi;
  while (bi * (bi + 1) / 2 > t) --bi;
  int bj = t - bi * (bi + 1) / 2;
  const char* Ab = (const char*)(Qb + ((size_t)b * 2048 + bi * 128) * 512);
  const char* Bb = (const char*)(Kb + ((size_t)b * 2048 + bj * 128) * 512);
  f32x4 acc[4][4] = {};
  KLOOP(Ab, Bb, 1024, 16, true);
  if (tid < 128) colred[tid] = 0.f;
  __syncthreads();
  const float expc = 1.4426950408889634f / 22.627416997969522f; // log2(e)/sqrt(512)
  int i0 = bi * 128 + wr * 64 + (lane >> 4) * 4;
  int lr = lane & 15;
  int jg0 = bj * 128 + wc * 64 + lr * 4;
  u16* Eb = E + (size_t)b * 2048 * 2048;
  float csum4[4] = {0.f, 0.f, 0.f, 0.f};
#pragma unroll
  for (int m = 0; m < 4; ++m)
#pragma unroll
    for (int r = 0; r < 4; ++r) {
      int ig = i0 + m * 16 + r;
      union { u16 us[4]; uint2 v; } pk;
#pragma unroll
      for (int n = 0; n < 4; ++n) {
        float e = (jg0 + n > ig) ? 0.f : exp2f(acc[m][n][r] * expc);
        pk.us[n] = f2bf(e);
        csum4[n] += e;
      }
      *(uint2*)&Eb[(size_t)ig * 2048 + jg0] = pk.v;
    }
#pragma unroll
  for (int n = 0; n < 4; ++n) {
    float v = csum4[n];
    v += __shfl_xor(v, 16);
    v += __shfl_xor(v, 32);
    if ((lane >> 4) == 0) atomicAdd(&colred[wc * 64 + lr * 4 + n], v);
  }
  __syncthreads();
  if (tid < 128) atomicAdd(&colsum[b * 2048 + bj * 128 + tid], colred[tid]);
}

// Vt[b][n][j] = Vb[b][j][n] / colsum[b][j]  (64x64 tiles)
__global__ __launch_bounds__(256) void vtrans(const u16* __restrict__ Vb, const float* __restrict__ colsum,
                                              u16* __restrict__ Vt) {
  __shared__ u16 tile[64][72];
  __shared__ float scale[64];
  int b = blockIdx.z, j0 = blockIdx.x * 64, n0 = blockIdx.y * 64;
  int t = threadIdx.x;
  if (t < 64) scale[t] = 1.f / colsum[b * 2048 + j0 + t];
#pragma unroll
  for (int p = 0; p < 2; ++p) {
    int c = t + p * 256, r = c >> 3, nf = (c & 7) * 8;
    *(uint4*)&tile[r][nf] = *(const uint4*)(Vb + ((size_t)(b * 2048 + j0 + r)) * 512 + n0 + nf);
  }
  __syncthreads();
#pragma unroll
  for (int p = 0; p < 2; ++p) {
    int c = t + p * 256, n = c >> 3, jf = (c & 7) * 8;
    union { u16 us[8]; uint4 v; } pk;
#pragma unroll
    for (int k = 0; k < 8; ++k) {
      uint32_t bits = ((uint32_t)tile[jf + k][n]) << 16;
      float v; __builtin_memcpy(&v, &bits, 4);
      pk.us[k] = f2bf(v * scale[jf + k]);
    }
    *(uint4*)(Vt + ((size_t)(b * 512 + n0 + n)) * 2048 + j0 + jf) = pk.v;
  }
}

// out[:, 512:] = E @ V'. One batch per XCD; CU-balanced mi pairing:
// slot s<32 gets mi=15-q, s>=32 gets mi=q  -> each CU's two blocks sum to 68 K-steps.
__global__ __launch_bounds__(256, 3) void pv_gemm(const u16* __restrict__ E, const u16* __restrict__ Vt,
                                                  float* __restrict__ out) {
  __shared__ __align__(16) char As[3][8192], Bs[3][8192];
  int tid = threadIdx.x, lane = tid & 63, wid = tid >> 6;
  int wr = wid >> 1, wc = wid & 1;
  int d = blockIdx.x;
  int b = d & 7, slot = d >> 3;        // batch per XCD; slot 0..63
  int s = slot & 31, half = slot >> 5, q = s >> 2, nj = s & 3;
  int mi = half ? q : 15 - q;
  const char* Ab = (const char*)(E + ((size_t)b * 2048 + mi * 128) * 2048);
  const char* Bb = (const char*)(Vt + ((size_t)b * 512 + nj * 128) * 2048);
  int NK = (mi + 1) * 4;
  f32x4 acc[4][4] = {};
  KLOOP(Ab, Bb, 4096, NK, false);
  int i0 = mi * 128 + wr * 64 + (lane >> 4) * 4;
  int n0 = 512 + nj * 128 + wc * 64 + (lane & 15);
  float* ob = out + (size_t)b * 2048 * 1024;
#pragma unroll
  for (int m = 0; m < 4; ++m)
#pragma unroll
    for (int n = 0; n < 4; ++n)
#pragma unroll
      for (int r = 0; r < 4; ++r)
        ob[(size_t)(i0 + m * 16 + r) * 1024 + n0 + n * 16] = acc[m][n][r];
}

// ---------------- launch ----------------

extern "C" void kernel_launch(void* const* d_in, const int* in_sizes, int n_in,
                              void* d_out, int out_size, void* d_ws, size_t ws_size,
                              hipStream_t stream) {
  const float* x  = (const float*)d_in[0];
  const float* Wq = (const float*)d_in[1];
  const float* bq = (const float*)d_in[2];
  const float* Wk = (const float*)d_in[3];
  const float* bk = (const float*)d_in[4];
  const float* Wv = (const float*)d_in[5];
  const float* bv = (const float*)d_in[6];
  float* out = (float*)d_out;
  char* ws = (char*)d_ws;

  // ws layout (bytes): Xb 16MB | Wb 1.5MB | Qb 16MB | Kb 16MB | Vb 16MB | Vt 16MB | E 64MB | colsum 64KB
  u16* Xb = (u16*)(ws);
  u16* Wb = (u16*)(ws + 16777216);
  u16* Qb = (u16*)(ws + 18350080);
  u16* Kb = (u16*)(ws + 35127296);
  u16* Vb = (u16*)(ws + 51904512);
  u16* Vt = (u16*)(ws + 68681728);
  u16* E  = (u16*)(ws + 85458944);
  float* colsum = (float*)(ws + 152567808);

  prep<<<4480, 256, 0, stream>>>(x, Wq, Wk, Wv, out, Xb, Wb, colsum);
  qkv_gemm<<<dim3(128, 12), 256, 0, stream>>>(Xb, Wb, bq, bk, bv, Qb, Kb, Vb);
  scores<<<1088, 256, 0, stream>>>(Qb, Kb, E, colsum);
  vtrans<<<dim3(32, 8, 8), 256, 0, stream>>>(Vb, colsum, Vt);
  pv_gemm<<<512, 256, 0, stream>>>(E, Vt, out);
}